// Round 1
// baseline (845.500 us; speedup 1.0000x reference)
//
#include <hip/hip_runtime.h>
#include <hip/hip_bf16.h>
#include <cstdint>

typedef unsigned int u32;
typedef unsigned long long u64;

#define ANUM 131072
#define BATCH 4
#define PRE 3000
#define CAP 4096
#define NW 47          /* ceil(3000/64) */
#define NWPAD 3008     /* 47*64 */
#define MAXOUT 1000

/* ---- workspace layout (bytes) ---- */
#define OFF_HIST1 0ul
#define OFF_HIST2 1048576ul
#define OFF_INFO  2097152ul            /* u32[256]: [0..3]=b16 [4..7]=c_above [8..11]=T [12..15]=candcnt [16..19]=keptcnt */
#define OFF_CAND  2098176ul            /* u64[B][CAP] */
#define OFF_ORDER 2229248ul            /* u32[B][PRE] */
#define OFF_SCORE 2277248ul            /* f32[B][PRE] */
#define OFF_BOXES 2325248ul            /* f32[B][PRE][6] */
#define OFF_MASKS 2613248ul            /* u64[B][NW][NWPAD]  (word-major, padded rows) */
#define OFF_KEPT  7137280ul            /* u32[B][PRE] */
#define MEMSET_BYTES 2098176ul         /* hists + info */

__device__ __forceinline__ u32 score_key(float f) {
  u32 u = __float_as_uint(f);
  return (u & 0x80000000u) ? ~u : (u | 0x80000000u);
}

/* ---------- 1. histogram of top 16 bits ---------- */
__global__ void k_hist1(const float* __restrict__ scores, u32* __restrict__ hist) {
  int t = blockIdx.x * blockDim.x + threadIdx.x;      /* 0 .. B*ANUM-1 */
  int b = t >> 17;
  u32 key = score_key(scores[t]);
  atomicAdd(&hist[(b << 16) + (key >> 16)], 1u);
}

/* ---------- 2. find high-16 bin crossing rank 3000 ---------- */
__global__ void k_sel1(const u32* __restrict__ hist, u32* __restrict__ info) {
  int b = blockIdx.x, tid = threadIdx.x;              /* 256 threads */
  __shared__ u32 part[256];
  const u32* h = hist + (b << 16);
  u32 s = 0;
  for (int r = tid * 256; r < tid * 256 + 256; ++r) s += h[65535 - r];
  part[tid] = s;
  __syncthreads();
  if (tid == 0) {
    u32 c = 0; int tstar = 0; u32 cb = 0;
    for (int t = 0; t < 256; ++t) {
      if (c + part[t] >= PRE) { tstar = t; cb = c; break; }
      c += part[t];
    }
    u32 cc = cb; int b16 = 0;
    for (int r = tstar * 256; r < 65536; ++r) {
      u32 cnt = h[65535 - r];
      if (cc + cnt >= PRE) { b16 = 65535 - r; break; }
      cc += cnt;
    }
    info[b] = (u32)b16;
    info[4 + b] = cc;                                  /* count strictly above bin */
  }
}

/* ---------- 3. histogram of low 16 bits within the boundary bin ---------- */
__global__ void k_hist2(const float* __restrict__ scores, const u32* __restrict__ info,
                        u32* __restrict__ hist2) {
  int t = blockIdx.x * blockDim.x + threadIdx.x;
  int b = t >> 17;
  u32 key = score_key(scores[t]);
  if ((key >> 16) == info[b])
    atomicAdd(&hist2[(b << 16) + (key & 0xFFFFu)], 1u);
}

/* ---------- 4. exact threshold key T ---------- */
__global__ void k_sel2(const u32* __restrict__ hist2, u32* __restrict__ info) {
  int b = blockIdx.x, tid = threadIdx.x;
  __shared__ u32 part[256];
  const u32* h = hist2 + (b << 16);
  u32 s = 0;
  for (int r = tid * 256; r < tid * 256 + 256; ++r) s += h[65535 - r];
  part[tid] = s;
  __syncthreads();
  if (tid == 0) {
    int target = PRE - (int)info[4 + b];               /* >=1 */
    u32 c = 0; int tstar = 0; u32 cb = 0;
    for (int t = 0; t < 256; ++t) {
      if ((int)(c + part[t]) >= target) { tstar = t; cb = c; break; }
      c += part[t];
    }
    u32 cc = cb; int t16 = 0;
    for (int r = tstar * 256; r < 65536; ++r) {
      u32 cnt = h[65535 - r];
      if ((int)(cc + cnt) >= target) { t16 = 65535 - r; break; }
      cc += cnt;
    }
    info[8 + b] = (info[b] << 16) | (u32)t16;          /* threshold key */
  }
}

/* ---------- 5. compact candidates (key >= T) ---------- */
__global__ void k_compact(const float* __restrict__ scores, u32* __restrict__ info,
                          u64* __restrict__ cand) {
  int t = blockIdx.x * blockDim.x + threadIdx.x;
  int b = t >> 17;
  int e = t & (ANUM - 1);
  u32 key = score_key(scores[t]);
  if (key >= info[8 + b]) {
    u32 pos = atomicAdd(&info[12 + b], 1u);
    if (pos < CAP) cand[(b << 12) + pos] = ((u64)key << 32) | (u32)(~(u32)e);
  }
}

/* ---------- 6. bitonic sort (descending) of 4096 candidates, emit order+scores ---------- */
__global__ __launch_bounds__(1024) void k_sort(const u64* __restrict__ cand,
                                               const u32* __restrict__ info,
                                               u32* __restrict__ order,
                                               float* __restrict__ scoresel) {
  int b = blockIdx.x, tid = threadIdx.x;
  __shared__ u64 s[CAP];
  u32 n = info[12 + b]; if (n > CAP) n = CAP;
  for (int i = tid; i < CAP; i += 1024) s[i] = (i < (int)n) ? cand[(b << 12) + i] : 0ull;
  __syncthreads();
  for (int k = 2; k <= CAP; k <<= 1) {
    for (int j = k >> 1; j > 0; j >>= 1) {
      for (int i = tid; i < CAP; i += 1024) {
        int ixj = i ^ j;
        if (ixj > i) {
          u64 a = s[i], c = s[ixj];
          bool up = ((i & k) == 0);                     /* descending overall */
          if (up ? (a < c) : (a > c)) { s[i] = c; s[ixj] = a; }
        }
      }
      __syncthreads();
    }
  }
  for (int i = tid; i < PRE; i += 1024) {
    u64 kv = s[i];
    u32 key = (u32)(kv >> 32);
    u32 e = ~((u32)kv);
    order[b * PRE + i] = e;
    u32 u = (key & 0x80000000u) ? (key ^ 0x80000000u) : ~key;
    scoresel[b * PRE + i] = __uint_as_float(u);
  }
}

/* ---------- 7. gather + box regression (no FMA contraction: match numpy) ---------- */
__global__ void k_regress(const float* __restrict__ anchors, const float* __restrict__ deltas,
                          const u32* __restrict__ order, float* __restrict__ boxes) {
  int t = blockIdx.x * blockDim.x + threadIdx.x;
  if (t >= BATCH * PRE) return;
  int b = t / PRE;
  u32 a = order[t];
  const float* an = anchors + (size_t)a * 6;
  const float* de = deltas + ((size_t)b * ANUM + a) * 6;
  float* out = boxes + (size_t)t * 6;
#pragma unroll
  for (int d = 0; d < 3; ++d) {
    float lo = an[d], hi = an[3 + d];
    float dims = __fsub_rn(hi, lo);
    float ctr = __fadd_rn(lo, __fmul_rn(0.5f, dims));
    ctr = __fadd_rn(ctr, __fmul_rn(de[d], dims));
    float nd = __fmul_rn(dims, expf(de[3 + d]));
    float h = __fmul_rn(0.5f, nd);
    out[d] = __fsub_rn(ctr, h);
    out[3 + d] = __fadd_rn(ctr, h);
  }
}

/* ---------- 8. suppression bitmask matrix ---------- */
__global__ void k_mask(const float* __restrict__ boxes, u64* __restrict__ masks) {
  int jblk = blockIdx.x, iblk = blockIdx.y, b = blockIdx.z;
  int tid = threadIdx.x;                                /* 64 */
  __shared__ float cb[64][7];                           /* col boxes + volume */
  int j0 = jblk * 64;
  {
    int jj = j0 + tid; if (jj > PRE - 1) jj = PRE - 1;
    const float* src = boxes + ((size_t)b * PRE + jj) * 6;
#pragma unroll
    for (int d = 0; d < 6; ++d) cb[tid][d] = src[d];
    float dx = fmaxf(__fsub_rn(cb[tid][3], cb[tid][0]), 0.0f);
    float dy = fmaxf(__fsub_rn(cb[tid][4], cb[tid][1]), 0.0f);
    float dz = fmaxf(__fsub_rn(cb[tid][5], cb[tid][2]), 0.0f);
    cb[tid][6] = __fmul_rn(__fmul_rn(dx, dy), dz);
  }
  __syncthreads();
  int i = iblk * 64 + tid;
  if (i >= PRE) return;
  u64 bits = 0;
  if (j0 + 63 > i) {
    const float* rb = boxes + ((size_t)b * PRE + i) * 6;
    float l0 = rb[0], l1 = rb[1], l2 = rb[2], h0 = rb[3], h1 = rb[4], h2 = rb[5];
    float dx = fmaxf(__fsub_rn(h0, l0), 0.0f);
    float dy = fmaxf(__fsub_rn(h1, l1), 0.0f);
    float dz = fmaxf(__fsub_rn(h2, l2), 0.0f);
    float vi = __fmul_rn(__fmul_rn(dx, dy), dz);
    for (int c = 0; c < 64; ++c) {
      int j = j0 + c;
      if (j > i && j < PRE) {
        float ix = fmaxf(__fsub_rn(fminf(h0, cb[c][3]), fmaxf(l0, cb[c][0])), 0.0f);
        float iy = fmaxf(__fsub_rn(fminf(h1, cb[c][4]), fmaxf(l1, cb[c][1])), 0.0f);
        float iz = fmaxf(__fsub_rn(fminf(h2, cb[c][5]), fmaxf(l2, cb[c][2])), 0.0f);
        float iv = __fmul_rn(__fmul_rn(ix, iy), iz);
        float un = fmaxf(__fsub_rn(__fadd_rn(vi, cb[c][6]), iv), 1e-8f);
        float iou = __fdiv_rn(iv, un);
        if (iou > 0.7f) bits |= (1ull << c);
      }
    }
  }
  /* word-major layout: lane streams column sequentially in the scan */
  masks[((size_t)(b * NW + jblk)) * NWPAD + i] = bits;
}

/* ---------- 9. sequential NMS scan (1 wave / batch) ---------- */
__global__ void k_scan(const u64* __restrict__ masks, u32* __restrict__ kept,
                       u32* __restrict__ info) {
  int b = blockIdx.x;
  int lane = threadIdx.x;                               /* 64 */
  bool active = lane < NW;
  const u64* col = masks + ((size_t)(b * NW + (active ? lane : NW - 1))) * NWPAD;
  u64 removed = 0;
  int cnt = 0;
  const int PF = 12;                                    /* 3000 = 12*250 */
  u64 cur[PF], nxt[PF];
#pragma unroll
  for (int p = 0; p < PF; ++p) cur[p] = active ? col[p] : 0ull;
  for (int base = 0; base < PRE; base += PF) {
#pragma unroll
    for (int p = 0; p < PF; ++p) {
      int nidx = base + PF + p;
      nxt[p] = (active && nidx < PRE) ? col[nidx] : 0ull;
    }
#pragma unroll
    for (int p = 0; p < PF; ++p) {
      int i = base + p;
      int w = i >> 6;
      u32 rlo = (u32)removed, rhi = (u32)(removed >> 32);
      rlo = __shfl(rlo, w);
      rhi = __shfl(rhi, w);
      u64 rw = ((u64)rhi << 32) | rlo;
      if (!((rw >> (i & 63)) & 1ull)) {                 /* alive: wave-uniform */
        removed |= cur[p];
        if (lane == 0) kept[b * PRE + cnt] = (u32)i;
        ++cnt;
      }
    }
#pragma unroll
    for (int p = 0; p < PF; ++p) cur[p] = nxt[p];
  }
  if (lane == 0) info[16 + b] = (u32)cnt;
}

/* ---------- 10. output assembly ---------- */
__global__ void k_out(const float* __restrict__ boxes, const float* __restrict__ scoresel,
                      const u32* __restrict__ kept, const u32* __restrict__ info,
                      float* __restrict__ out) {
  int b = blockIdx.x, tid = threadIdx.x;                /* 256 */
  int cnt = (int)info[16 + b]; if (cnt > MAXOUT) cnt = MAXOUT;
  for (int k = tid; k < MAXOUT; k += 256) {
    float pr[6] = {0.f, 0.f, 0.f, 0.f, 0.f, 0.f};
    float s = 0.f, v = 0.f;
    if (k < cnt) {
      u32 i = kept[b * PRE + k];
      const float* bx = boxes + ((size_t)b * PRE + i) * 6;
#pragma unroll
      for (int d = 0; d < 6; ++d) pr[d] = bx[d];
      s = scoresel[b * PRE + i];
      v = 1.f;
    }
    float* pp = out + ((size_t)(b * MAXOUT + k)) * 6;
#pragma unroll
    for (int d = 0; d < 6; ++d) pp[d] = pr[d];
    out[BATCH * MAXOUT * 6 + b * MAXOUT + k] = s;
    out[BATCH * MAXOUT * 7 + b * MAXOUT + k] = (float)b;
    out[BATCH * MAXOUT * 8 + b * MAXOUT + k] = v;
  }
}

extern "C" void kernel_launch(void* const* d_in, const int* in_sizes, int n_in,
                              void* d_out, int out_size, void* d_ws, size_t ws_size,
                              hipStream_t stream) {
  const float* anchors = (const float*)d_in[0];
  const float* scores  = (const float*)d_in[1];
  const float* deltas  = (const float*)d_in[2];
  float* out = (float*)d_out;

  char* w = (char*)d_ws;
  u32* hist1   = (u32*)(w + OFF_HIST1);
  u32* hist2   = (u32*)(w + OFF_HIST2);
  u32* info    = (u32*)(w + OFF_INFO);
  u64* cand    = (u64*)(w + OFF_CAND);
  u32* order   = (u32*)(w + OFF_ORDER);
  float* scoresel = (float*)(w + OFF_SCORE);
  float* boxes = (float*)(w + OFF_BOXES);
  u64* masks   = (u64*)(w + OFF_MASKS);
  u32* kept    = (u32*)(w + OFF_KEPT);

  hipMemsetAsync(d_ws, 0, MEMSET_BYTES, stream);

  int nElem = BATCH * ANUM;
  k_hist1<<<nElem / 256, 256, 0, stream>>>(scores, hist1);
  k_sel1<<<BATCH, 256, 0, stream>>>(hist1, info);
  k_hist2<<<nElem / 256, 256, 0, stream>>>(scores, info, hist2);
  k_sel2<<<BATCH, 256, 0, stream>>>(hist2, info);
  k_compact<<<nElem / 256, 256, 0, stream>>>(scores, info, cand);
  k_sort<<<BATCH, 1024, 0, stream>>>(cand, info, order, scoresel);
  k_regress<<<(BATCH * PRE + 255) / 256, 256, 0, stream>>>(anchors, deltas, order, boxes);
  k_mask<<<dim3(NW, NW, BATCH), 64, 0, stream>>>(boxes, masks);
  k_scan<<<BATCH, 64, 0, stream>>>(masks, kept, info);
  k_out<<<BATCH, 256, 0, stream>>>(boxes, scoresel, kept, info, out);
}

// Round 2
// 516.435 us; speedup vs baseline: 1.6372x; 1.6372x over previous
//
#include <hip/hip_runtime.h>
#include <hip/hip_bf16.h>
#include <cstdint>

typedef unsigned int u32;
typedef unsigned long long u64;

#define ANUM 131072
#define BATCH 4
#define PRE 3000
#define CAP 4096
#define NW 47          /* ceil(3000/64) */
#define MAXOUT 1000

/* ---- workspace layout (bytes) ---- */
#define OFF_HIST1 0ul
#define OFF_HIST2 1048576ul
#define OFF_INFO  2097152ul            /* u32[256]: [0..3]=b16 [4..7]=c_above [8..11]=T [12..15]=candcnt [16..19]=keptcnt */
#define OFF_CAND  2098176ul            /* u64[B][CAP] */
#define OFF_ORDER 2229248ul            /* u32[B][PRE] */
#define OFF_SCORE 2277248ul            /* f32[B][PRE] */
#define OFF_BOXES 2325248ul            /* f32[B][PRE][6] */
#define OFF_MASKS 2613248ul            /* u64[B][PRE][NW]  (row-major) */
#define OFF_KEPT  7125248ul            /* u32[B][PRE] */
#define MEMSET_BYTES 2098176ul         /* hists + info */

__device__ __forceinline__ u32 score_key(float f) {
  u32 u = __float_as_uint(f);
  return (u & 0x80000000u) ? ~u : (u | 0x80000000u);
}

/* ---------- 1. histogram of top 16 bits ---------- */
__global__ void k_hist1(const float* __restrict__ scores, u32* __restrict__ hist) {
  int t = blockIdx.x * blockDim.x + threadIdx.x;      /* 0 .. B*ANUM-1 */
  int b = t >> 17;
  u32 key = score_key(scores[t]);
  atomicAdd(&hist[(b << 16) + (key >> 16)], 1u);
}

/* ---------- 2. find high-16 bin crossing rank 3000 ---------- */
__global__ void k_sel1(const u32* __restrict__ hist, u32* __restrict__ info) {
  int b = blockIdx.x, tid = threadIdx.x;              /* 256 threads */
  __shared__ u32 part[256];
  const u32* h = hist + (b << 16);
  u32 s = 0;
  for (int r = tid * 256; r < tid * 256 + 256; ++r) s += h[65535 - r];
  part[tid] = s;
  __syncthreads();
  if (tid == 0) {
    u32 c = 0; int tstar = 0; u32 cb = 0;
    for (int t = 0; t < 256; ++t) {
      if (c + part[t] >= PRE) { tstar = t; cb = c; break; }
      c += part[t];
    }
    u32 cc = cb; int b16 = 0;
    for (int r = tstar * 256; r < 65536; ++r) {
      u32 cnt = h[65535 - r];
      if (cc + cnt >= PRE) { b16 = 65535 - r; break; }
      cc += cnt;
    }
    info[b] = (u32)b16;
    info[4 + b] = cc;                                  /* count strictly above bin */
  }
}

/* ---------- 3. histogram of low 16 bits within the boundary bin ---------- */
__global__ void k_hist2(const float* __restrict__ scores, const u32* __restrict__ info,
                        u32* __restrict__ hist2) {
  int t = blockIdx.x * blockDim.x + threadIdx.x;
  int b = t >> 17;
  u32 key = score_key(scores[t]);
  if ((key >> 16) == info[b])
    atomicAdd(&hist2[(b << 16) + (key & 0xFFFFu)], 1u);
}

/* ---------- 4. exact threshold key T ---------- */
__global__ void k_sel2(const u32* __restrict__ hist2, u32* __restrict__ info) {
  int b = blockIdx.x, tid = threadIdx.x;
  __shared__ u32 part[256];
  const u32* h = hist2 + (b << 16);
  u32 s = 0;
  for (int r = tid * 256; r < tid * 256 + 256; ++r) s += h[65535 - r];
  part[tid] = s;
  __syncthreads();
  if (tid == 0) {
    int target = PRE - (int)info[4 + b];               /* >=1 */
    u32 c = 0; int tstar = 0; u32 cb = 0;
    for (int t = 0; t < 256; ++t) {
      if ((int)(c + part[t]) >= target) { tstar = t; cb = c; break; }
      c += part[t];
    }
    u32 cc = cb; int t16 = 0;
    for (int r = tstar * 256; r < 65536; ++r) {
      u32 cnt = h[65535 - r];
      if ((int)(cc + cnt) >= target) { t16 = 65535 - r; break; }
      cc += cnt;
    }
    info[8 + b] = (info[b] << 16) | (u32)t16;          /* threshold key */
  }
}

/* ---------- 5. compact candidates (key >= T) ---------- */
__global__ void k_compact(const float* __restrict__ scores, u32* __restrict__ info,
                          u64* __restrict__ cand) {
  int t = blockIdx.x * blockDim.x + threadIdx.x;
  int b = t >> 17;
  int e = t & (ANUM - 1);
  u32 key = score_key(scores[t]);
  if (key >= info[8 + b]) {
    u32 pos = atomicAdd(&info[12 + b], 1u);
    if (pos < CAP) cand[(b << 12) + pos] = ((u64)key << 32) | (u32)(~(u32)e);
  }
}

/* ---------- 6. bitonic sort (descending) of 4096 candidates, emit order+scores ---------- */
__global__ __launch_bounds__(1024) void k_sort(const u64* __restrict__ cand,
                                               const u32* __restrict__ info,
                                               u32* __restrict__ order,
                                               float* __restrict__ scoresel) {
  int b = blockIdx.x, tid = threadIdx.x;
  __shared__ u64 s[CAP];
  u32 n = info[12 + b]; if (n > CAP) n = CAP;
  for (int i = tid; i < CAP; i += 1024) s[i] = (i < (int)n) ? cand[(b << 12) + i] : 0ull;
  __syncthreads();
  for (int k = 2; k <= CAP; k <<= 1) {
    for (int j = k >> 1; j > 0; j >>= 1) {
      for (int i = tid; i < CAP; i += 1024) {
        int ixj = i ^ j;
        if (ixj > i) {
          u64 a = s[i], c = s[ixj];
          bool up = ((i & k) == 0);                     /* descending overall */
          if (up ? (a < c) : (a > c)) { s[i] = c; s[ixj] = a; }
        }
      }
      __syncthreads();
    }
  }
  for (int i = tid; i < PRE; i += 1024) {
    u64 kv = s[i];
    u32 key = (u32)(kv >> 32);
    u32 e = ~((u32)kv);
    order[b * PRE + i] = e;
    u32 u = (key & 0x80000000u) ? (key ^ 0x80000000u) : ~key;
    scoresel[b * PRE + i] = __uint_as_float(u);
  }
}

/* ---------- 7. gather + box regression (no FMA contraction: match numpy) ---------- */
__global__ void k_regress(const float* __restrict__ anchors, const float* __restrict__ deltas,
                          const u32* __restrict__ order, float* __restrict__ boxes) {
  int t = blockIdx.x * blockDim.x + threadIdx.x;
  if (t >= BATCH * PRE) return;
  int b = t / PRE;
  u32 a = order[t];
  const float* an = anchors + (size_t)a * 6;
  const float* de = deltas + ((size_t)b * ANUM + a) * 6;
  float* out = boxes + (size_t)t * 6;
#pragma unroll
  for (int d = 0; d < 3; ++d) {
    float lo = an[d], hi = an[3 + d];
    float dims = __fsub_rn(hi, lo);
    float ctr = __fadd_rn(lo, __fmul_rn(0.5f, dims));
    ctr = __fadd_rn(ctr, __fmul_rn(de[d], dims));
    float nd = __fmul_rn(dims, expf(de[3 + d]));
    float h = __fmul_rn(0.5f, nd);
    out[d] = __fsub_rn(ctr, h);
    out[3 + d] = __fadd_rn(ctr, h);
  }
}

/* ---------- 8. suppression bitmask matrix (row-major output) ---------- */
__global__ void k_mask(const float* __restrict__ boxes, u64* __restrict__ masks) {
  int jblk = blockIdx.x, iblk = blockIdx.y, b = blockIdx.z;
  int tid = threadIdx.x;                                /* 64 */
  __shared__ float cb[64][7];                           /* col boxes + volume */
  int j0 = jblk * 64;
  {
    int jj = j0 + tid; if (jj > PRE - 1) jj = PRE - 1;
    const float* src = boxes + ((size_t)b * PRE + jj) * 6;
#pragma unroll
    for (int d = 0; d < 6; ++d) cb[tid][d] = src[d];
    float dx = fmaxf(__fsub_rn(cb[tid][3], cb[tid][0]), 0.0f);
    float dy = fmaxf(__fsub_rn(cb[tid][4], cb[tid][1]), 0.0f);
    float dz = fmaxf(__fsub_rn(cb[tid][5], cb[tid][2]), 0.0f);
    cb[tid][6] = __fmul_rn(__fmul_rn(dx, dy), dz);
  }
  __syncthreads();
  int i = iblk * 64 + tid;
  if (i >= PRE) return;
  u64 bits = 0;
  if (j0 + 63 > i) {
    const float* rb = boxes + ((size_t)b * PRE + i) * 6;
    float l0 = rb[0], l1 = rb[1], l2 = rb[2], h0 = rb[3], h1 = rb[4], h2 = rb[5];
    float dx = fmaxf(__fsub_rn(h0, l0), 0.0f);
    float dy = fmaxf(__fsub_rn(h1, l1), 0.0f);
    float dz = fmaxf(__fsub_rn(h2, l2), 0.0f);
    float vi = __fmul_rn(__fmul_rn(dx, dy), dz);
    for (int c = 0; c < 64; ++c) {
      int j = j0 + c;
      if (j > i && j < PRE) {
        float ix = fmaxf(__fsub_rn(fminf(h0, cb[c][3]), fmaxf(l0, cb[c][0])), 0.0f);
        float iy = fmaxf(__fsub_rn(fminf(h1, cb[c][4]), fmaxf(l1, cb[c][1])), 0.0f);
        float iz = fmaxf(__fsub_rn(fminf(h2, cb[c][5]), fmaxf(l2, cb[c][2])), 0.0f);
        float iv = __fmul_rn(__fmul_rn(ix, iy), iz);
        float un = fmaxf(__fsub_rn(__fadd_rn(vi, cb[c][6]), iv), 1e-8f);
        float iou = __fdiv_rn(iv, un);
        if (iou > 0.7f) bits |= (1ull << c);
      }
    }
  }
  /* row-major: masks[b][i][w] */
  masks[((size_t)b * PRE + i) * NW + jblk] = bits;
}

/* ---------- 9. chunked sequential NMS scan (1 wave / batch) ----------
 * Per 64-box chunk:
 *  - intra-chunk: serial 64-step resolve on register-resident row words
 *    (readlane extraction is off the dependency chain)
 *  - inter-chunk: lane w accumulates rem_w |= OR(kept rows' word w),
 *    uniform-predicated selects, loads issued at chunk top (latency hidden)
 */
__global__ __launch_bounds__(64) void k_scan(const u64* __restrict__ masks,
                                             u32* __restrict__ kept,
                                             u32* __restrict__ info) {
  int b = blockIdx.x;
  int lane = threadIdx.x;                               /* 64 */
  const u64* M = masks + (size_t)b * PRE * NW;
  int wl = lane < NW ? lane : NW - 1;
  u64 rem = 0;                                          /* lane w: removed bits, boxes w*64.. */
  int cnt = 0;

  /* prefetch intra word for chunk 0 (rows 0..63, word 0) */
  u64 intra = M[(size_t)lane * NW + 0];

  for (int c = 0; c < NW; ++c) {
    int base = c * 64;
    int nrow = (base + 64 <= PRE) ? 64 : (PRE - base);

    /* issue this chunk's row loads (lane w reads word w of rows base..base+63) */
    u64 rows[64];
#pragma unroll
    for (int k = 0; k < 64; ++k) {
      int rk = base + (k < nrow ? k : nrow - 1);
      rows[k] = M[(size_t)rk * NW + wl];
    }
    /* prefetch next chunk's intra word */
    u64 intra_n = 0;
    if (c + 1 < NW) {
      int nb = base + 64;
      int nn = (nb + 64 <= PRE) ? 64 : (PRE - nb);
      int rn = nb + (lane < nn ? lane : nn - 1);
      intra_n = M[(size_t)rn * NW + (c + 1)];
    }

    /* alive0 = ~rem[chunk c] (broadcast from lane c), clipped to valid rows */
    u32 rlo = __shfl((u32)rem, c);
    u32 rhi = __shfl((u32)(rem >> 32), c);
    u64 rowmask = (nrow == 64) ? ~0ull : ((1ull << nrow) - 1ull);
    u64 alive = (~(((u64)rhi << 32) | rlo)) & rowmask;

    /* serial intra-chunk resolution (uniform across lanes) */
    u32 ilo = (u32)intra, ihi = (u32)(intra >> 32);
#pragma unroll
    for (int k = 0; k < 64; ++k) {
      u64 rw = ((u64)(u32)__builtin_amdgcn_readlane((int)ihi, k) << 32) |
               (u32)__builtin_amdgcn_readlane((int)ilo, k);
      alive &= ~(((alive >> k) & 1ull) ? rw : 0ull);
    }

    /* emit kept indices in ascending order */
    u64 ltmask = (lane == 0) ? 0ull : (~0ull >> (64 - lane));
    int pos = __popcll(alive & ltmask);
    if ((alive >> lane) & 1ull) kept[b * PRE + cnt + pos] = (u32)(base + lane);
    cnt += (int)__popcll(alive);

    /* propagate suppression of kept rows to all future words */
#pragma unroll
    for (int k = 0; k < 64; ++k) {
      rem |= (((alive >> k) & 1ull) ? rows[k] : 0ull);
    }
    intra = intra_n;
  }
  if (lane == 0) info[16 + b] = (u32)cnt;
}

/* ---------- 10. output assembly ---------- */
__global__ void k_out(const float* __restrict__ boxes, const float* __restrict__ scoresel,
                      const u32* __restrict__ kept, const u32* __restrict__ info,
                      float* __restrict__ out) {
  int b = blockIdx.x, tid = threadIdx.x;                /* 256 */
  int cnt = (int)info[16 + b]; if (cnt > MAXOUT) cnt = MAXOUT;
  for (int k = tid; k < MAXOUT; k += 256) {
    float pr[6] = {0.f, 0.f, 0.f, 0.f, 0.f, 0.f};
    float s = 0.f, v = 0.f;
    if (k < cnt) {
      u32 i = kept[b * PRE + k];
      const float* bx = boxes + ((size_t)b * PRE + i) * 6;
#pragma unroll
      for (int d = 0; d < 6; ++d) pr[d] = bx[d];
      s = scoresel[b * PRE + i];
      v = 1.f;
    }
    float* pp = out + ((size_t)(b * MAXOUT + k)) * 6;
#pragma unroll
    for (int d = 0; d < 6; ++d) pp[d] = pr[d];
    out[BATCH * MAXOUT * 6 + b * MAXOUT + k] = s;
    out[BATCH * MAXOUT * 7 + b * MAXOUT + k] = (float)b;
    out[BATCH * MAXOUT * 8 + b * MAXOUT + k] = v;
  }
}

extern "C" void kernel_launch(void* const* d_in, const int* in_sizes, int n_in,
                              void* d_out, int out_size, void* d_ws, size_t ws_size,
                              hipStream_t stream) {
  const float* anchors = (const float*)d_in[0];
  const float* scores  = (const float*)d_in[1];
  const float* deltas  = (const float*)d_in[2];
  float* out = (float*)d_out;

  char* w = (char*)d_ws;
  u32* hist1   = (u32*)(w + OFF_HIST1);
  u32* hist2   = (u32*)(w + OFF_HIST2);
  u32* info    = (u32*)(w + OFF_INFO);
  u64* cand    = (u64*)(w + OFF_CAND);
  u32* order   = (u32*)(w + OFF_ORDER);
  float* scoresel = (float*)(w + OFF_SCORE);
  float* boxes = (float*)(w + OFF_BOXES);
  u64* masks   = (u64*)(w + OFF_MASKS);
  u32* kept    = (u32*)(w + OFF_KEPT);

  hipMemsetAsync(d_ws, 0, MEMSET_BYTES, stream);

  int nElem = BATCH * ANUM;
  k_hist1<<<nElem / 256, 256, 0, stream>>>(scores, hist1);
  k_sel1<<<BATCH, 256, 0, stream>>>(hist1, info);
  k_hist2<<<nElem / 256, 256, 0, stream>>>(scores, info, hist2);
  k_sel2<<<BATCH, 256, 0, stream>>>(hist2, info);
  k_compact<<<nElem / 256, 256, 0, stream>>>(scores, info, cand);
  k_sort<<<BATCH, 1024, 0, stream>>>(cand, info, order, scoresel);
  k_regress<<<(BATCH * PRE + 255) / 256, 256, 0, stream>>>(anchors, deltas, order, boxes);
  k_mask<<<dim3(NW, NW, BATCH), 64, 0, stream>>>(boxes, masks);
  k_scan<<<BATCH, 64, 0, stream>>>(masks, kept, info);
  k_out<<<BATCH, 256, 0, stream>>>(boxes, scoresel, kept, info, out);
}

// Round 3
// 381.650 us; speedup vs baseline: 2.2154x; 1.3532x over previous
//
#include <hip/hip_runtime.h>
#include <hip/hip_bf16.h>
#include <cstdint>

typedef unsigned int u32;
typedef unsigned long long u64;

#define ANUM 131072
#define BATCH 4
#define PRE 3000
#define CAP 4096
#define NW 47          /* ceil(3000/64) */
#define MAXOUT 1000
#define NBUCK 64       /* candidate buckets per batch */
#define BCAP 256       /* slots per bucket (lambda~52, overflow impossible) */

/* ---- workspace layout (bytes) ----
 * cand aliases hist1 (hist1 dead after k_sel1, cand written by k_compact later)
 */
#define OFF_CAND  0ul                  /* u64[B][NBUCK][BCAP] = 512KB (aliases hist1) */
#define OFF_HIST1 0ul                  /* u32[B][65536] = 1MB */
#define OFF_HIST2 1048576ul            /* u32[B][65536] = 1MB */
#define OFF_INFO  2097152ul            /* u32[256]: [0..3]=b16 [4..7]=c_above [8..11]=T [16..19]=keptcnt */
#define OFF_BCNT  2098176ul            /* u32[B*NBUCK*16] (64B-padded counters) = 16KB */
#define OFF_ORDER 2114560ul            /* u32[B][PRE] */
#define OFF_SCORE 2162560ul            /* f32[B][PRE] */
#define OFF_BOXES 2210560ul            /* f32[B][PRE][6] */
#define OFF_MASKS 2498560ul            /* u64[B][PRE][NW] (row-major) = 4512000 */
#define OFF_KEPT  7010560ul            /* u32[B][PRE] */
#define MEMSET_BYTES 2114560ul         /* hists + info + bcnt */

__device__ __forceinline__ u32 score_key(float f) {
  u32 u = __float_as_uint(f);
  return (u & 0x80000000u) ? ~u : (u | 0x80000000u);
}

/* ---------- 1. histogram of top 16 bits ---------- */
__global__ void k_hist1(const float* __restrict__ scores, u32* __restrict__ hist) {
  int t = blockIdx.x * blockDim.x + threadIdx.x;      /* 0 .. B*ANUM-1 */
  int b = t >> 17;
  u32 key = score_key(scores[t]);
  atomicAdd(&hist[(b << 16) + (key >> 16)], 1u);
}

/* ---------- 2. find high-16 bin crossing rank 3000 ---------- */
__global__ void k_sel1(const u32* __restrict__ hist, u32* __restrict__ info) {
  int b = blockIdx.x, tid = threadIdx.x;              /* 256 threads */
  __shared__ u32 part[256];
  const u32* h = hist + (b << 16);
  u32 s = 0;
  for (int r = tid * 256; r < tid * 256 + 256; ++r) s += h[65535 - r];
  part[tid] = s;
  __syncthreads();
  if (tid == 0) {
    u32 c = 0; int tstar = 0; u32 cb = 0;
    for (int t = 0; t < 256; ++t) {
      if (c + part[t] >= PRE) { tstar = t; cb = c; break; }
      c += part[t];
    }
    u32 cc = cb; int b16 = 0;
    for (int r = tstar * 256; r < 65536; ++r) {
      u32 cnt = h[65535 - r];
      if (cc + cnt >= PRE) { b16 = 65535 - r; break; }
      cc += cnt;
    }
    info[b] = (u32)b16;
    info[4 + b] = cc;                                  /* count strictly above bin */
  }
}

/* ---------- 3. histogram of low 16 bits within the boundary bin ---------- */
__global__ void k_hist2(const float* __restrict__ scores, const u32* __restrict__ info,
                        u32* __restrict__ hist2) {
  int t = blockIdx.x * blockDim.x + threadIdx.x;
  int b = t >> 17;
  u32 key = score_key(scores[t]);
  if ((key >> 16) == info[b])
    atomicAdd(&hist2[(b << 16) + (key & 0xFFFFu)], 1u);
}

/* ---------- 4. exact threshold key T ---------- */
__global__ void k_sel2(const u32* __restrict__ hist2, u32* __restrict__ info) {
  int b = blockIdx.x, tid = threadIdx.x;
  __shared__ u32 part[256];
  const u32* h = hist2 + (b << 16);
  u32 s = 0;
  for (int r = tid * 256; r < tid * 256 + 256; ++r) s += h[65535 - r];
  part[tid] = s;
  __syncthreads();
  if (tid == 0) {
    int target = PRE - (int)info[4 + b];               /* >=1 */
    u32 c = 0; int tstar = 0; u32 cb = 0;
    for (int t = 0; t < 256; ++t) {
      if ((int)(c + part[t]) >= target) { tstar = t; cb = c; break; }
      c += part[t];
    }
    u32 cc = cb; int t16 = 0;
    for (int r = tstar * 256; r < 65536; ++r) {
      u32 cnt = h[65535 - r];
      if ((int)(cc + cnt) >= target) { t16 = 65535 - r; break; }
      cc += cnt;
    }
    info[8 + b] = (info[b] << 16) | (u32)t16;          /* threshold key */
  }
}

/* ---------- 5. compact candidates (key >= T) into per-bucket lists ----------
 * 64 buckets/batch; each counter lives in its own 64B line -> no same-line
 * atomic serialization (round-2 bottleneck: 139us on one hot line).
 */
__global__ void k_compact(const float* __restrict__ scores, const u32* __restrict__ info,
                          u32* __restrict__ bcnt, u64* __restrict__ cand) {
  int t = blockIdx.x * blockDim.x + threadIdx.x;
  int b = t >> 17;
  int e = t & (ANUM - 1);
  int bucket = (blockIdx.x >> 3) & (NBUCK - 1);        /* 8 consecutive blocks/bucket */
  u32 key = score_key(scores[t]);
  if (key >= info[8 + b]) {
    u32 pos = atomicAdd(&bcnt[(u32)((b << 6) + bucket) * 16u], 1u);
    if (pos < BCAP) cand[(size_t)((b << 6) + bucket) * BCAP + pos] = ((u64)key << 32) | (u32)(~(u32)e);
  }
}

/* ---------- 6. gather buckets + bitonic sort (descending), emit order+scores ---------- */
__global__ __launch_bounds__(1024) void k_sort(const u64* __restrict__ cand,
                                               const u32* __restrict__ bcnt,
                                               u32* __restrict__ order,
                                               float* __restrict__ scoresel) {
  int b = blockIdx.x, tid = threadIdx.x;
  __shared__ u64 s[CAP];
  __shared__ u32 pref[NBUCK + 1];
  if (tid < NBUCK) {                                   /* wave 0: scan bucket counts */
    u32 c = bcnt[(u32)((b << 6) + tid) * 16u];
    if (c > BCAP) c = BCAP;
    u32 inc = c;
#pragma unroll
    for (int d = 1; d < 64; d <<= 1) {
      u32 v = __shfl_up(inc, d);
      if (tid >= d) inc += v;
    }
    pref[tid + 1] = inc;
    if (tid == 0) pref[0] = 0;
  }
  __syncthreads();
  for (int i = tid; i < CAP; i += 1024) s[i] = 0ull;   /* zero pads sort below real keys */
  __syncthreads();
  for (int j = tid; j < NBUCK * BCAP; j += 1024) {
    int bk = j >> 8, sl = j & (BCAP - 1);
    u32 c = pref[bk + 1] - pref[bk];
    if ((u32)sl < c) s[pref[bk] + sl] = cand[(size_t)((b << 6) + bk) * BCAP + sl];
  }
  __syncthreads();
  for (int k = 2; k <= CAP; k <<= 1) {
    for (int j = k >> 1; j > 0; j >>= 1) {
      for (int i = tid; i < CAP; i += 1024) {
        int ixj = i ^ j;
        if (ixj > i) {
          u64 a = s[i], c = s[ixj];
          bool up = ((i & k) == 0);                     /* descending overall */
          if (up ? (a < c) : (a > c)) { s[i] = c; s[ixj] = a; }
        }
      }
      __syncthreads();
    }
  }
  for (int i = tid; i < PRE; i += 1024) {
    u64 kv = s[i];
    u32 key = (u32)(kv >> 32);
    u32 e = ~((u32)kv);
    order[b * PRE + i] = e;
    u32 u = (key & 0x80000000u) ? (key ^ 0x80000000u) : ~key;
    scoresel[b * PRE + i] = __uint_as_float(u);
  }
}

/* ---------- 7. gather + box regression (no FMA contraction: match numpy) ---------- */
__global__ void k_regress(const float* __restrict__ anchors, const float* __restrict__ deltas,
                          const u32* __restrict__ order, float* __restrict__ boxes) {
  int t = blockIdx.x * blockDim.x + threadIdx.x;
  if (t >= BATCH * PRE) return;
  int b = t / PRE;
  u32 a = order[t];
  const float* an = anchors + (size_t)a * 6;
  const float* de = deltas + ((size_t)b * ANUM + a) * 6;
  float* out = boxes + (size_t)t * 6;
#pragma unroll
  for (int d = 0; d < 3; ++d) {
    float lo = an[d], hi = an[3 + d];
    float dims = __fsub_rn(hi, lo);
    float ctr = __fadd_rn(lo, __fmul_rn(0.5f, dims));
    ctr = __fadd_rn(ctr, __fmul_rn(de[d], dims));
    float nd = __fmul_rn(dims, expf(de[3 + d]));
    float h = __fmul_rn(0.5f, nd);
    out[d] = __fsub_rn(ctr, h);
    out[3 + d] = __fadd_rn(ctr, h);
  }
}

/* ---------- 8. suppression bitmask matrix (row-major output) ---------- */
__global__ void k_mask(const float* __restrict__ boxes, u64* __restrict__ masks) {
  int jblk = blockIdx.x, iblk = blockIdx.y, b = blockIdx.z;
  int tid = threadIdx.x;                                /* 64 */
  __shared__ float cb[64][7];                           /* col boxes + volume */
  int j0 = jblk * 64;
  {
    int jj = j0 + tid; if (jj > PRE - 1) jj = PRE - 1;
    const float* src = boxes + ((size_t)b * PRE + jj) * 6;
#pragma unroll
    for (int d = 0; d < 6; ++d) cb[tid][d] = src[d];
    float dx = fmaxf(__fsub_rn(cb[tid][3], cb[tid][0]), 0.0f);
    float dy = fmaxf(__fsub_rn(cb[tid][4], cb[tid][1]), 0.0f);
    float dz = fmaxf(__fsub_rn(cb[tid][5], cb[tid][2]), 0.0f);
    cb[tid][6] = __fmul_rn(__fmul_rn(dx, dy), dz);
  }
  __syncthreads();
  int i = iblk * 64 + tid;
  if (i >= PRE) return;
  u64 bits = 0;
  if (j0 + 63 > i) {
    const float* rb = boxes + ((size_t)b * PRE + i) * 6;
    float l0 = rb[0], l1 = rb[1], l2 = rb[2], h0 = rb[3], h1 = rb[4], h2 = rb[5];
    float dx = fmaxf(__fsub_rn(h0, l0), 0.0f);
    float dy = fmaxf(__fsub_rn(h1, l1), 0.0f);
    float dz = fmaxf(__fsub_rn(h2, l2), 0.0f);
    float vi = __fmul_rn(__fmul_rn(dx, dy), dz);
    for (int c = 0; c < 64; ++c) {
      int j = j0 + c;
      if (j > i && j < PRE) {
        float ix = fmaxf(__fsub_rn(fminf(h0, cb[c][3]), fmaxf(l0, cb[c][0])), 0.0f);
        float iy = fmaxf(__fsub_rn(fminf(h1, cb[c][4]), fmaxf(l1, cb[c][1])), 0.0f);
        float iz = fmaxf(__fsub_rn(fminf(h2, cb[c][5]), fmaxf(l2, cb[c][2])), 0.0f);
        float iv = __fmul_rn(__fmul_rn(ix, iy), iz);
        float un = fmaxf(__fsub_rn(__fadd_rn(vi, cb[c][6]), iv), 1e-8f);
        float iou = __fdiv_rn(iv, un);
        if (iou > 0.7f) bits |= (1ull << c);
      }
    }
  }
  /* row-major: masks[b][i][w] */
  masks[((size_t)b * PRE + i) * NW + jblk] = bits;
}

/* ---------- 9. chunked sequential NMS scan (1 wave / batch) ---------- */
__global__ __launch_bounds__(64) void k_scan(const u64* __restrict__ masks,
                                             u32* __restrict__ kept,
                                             u32* __restrict__ info) {
  int b = blockIdx.x;
  int lane = threadIdx.x;                               /* 64 */
  const u64* M = masks + (size_t)b * PRE * NW;
  int wl = lane < NW ? lane : NW - 1;
  u64 rem = 0;                                          /* lane w: removed bits, boxes w*64.. */
  int cnt = 0;

  /* prefetch intra word for chunk 0 (rows 0..63, word 0) */
  u64 intra = M[(size_t)lane * NW + 0];

  for (int c = 0; c < NW; ++c) {
    int base = c * 64;
    int nrow = (base + 64 <= PRE) ? 64 : (PRE - base);

    /* issue this chunk's row loads (lane w reads word w of rows base..base+63) */
    u64 rows[64];
#pragma unroll
    for (int k = 0; k < 64; ++k) {
      int rk = base + (k < nrow ? k : nrow - 1);
      rows[k] = M[(size_t)rk * NW + wl];
    }
    /* prefetch next chunk's intra word */
    u64 intra_n = 0;
    if (c + 1 < NW) {
      int nb = base + 64;
      int nn = (nb + 64 <= PRE) ? 64 : (PRE - nb);
      int rn = nb + (lane < nn ? lane : nn - 1);
      intra_n = M[(size_t)rn * NW + (c + 1)];
    }

    /* alive0 = ~rem[chunk c] (broadcast from lane c), clipped to valid rows */
    u32 rlo = __shfl((u32)rem, c);
    u32 rhi = __shfl((u32)(rem >> 32), c);
    u64 rowmask = (nrow == 64) ? ~0ull : ((1ull << nrow) - 1ull);
    u64 alive = (~(((u64)rhi << 32) | rlo)) & rowmask;

    /* serial intra-chunk resolution (uniform across lanes) */
    u32 ilo = (u32)intra, ihi = (u32)(intra >> 32);
#pragma unroll
    for (int k = 0; k < 64; ++k) {
      u64 rw = ((u64)(u32)__builtin_amdgcn_readlane((int)ihi, k) << 32) |
               (u32)__builtin_amdgcn_readlane((int)ilo, k);
      alive &= ~(((alive >> k) & 1ull) ? rw : 0ull);
    }

    /* emit kept indices in ascending order */
    u64 ltmask = (lane == 0) ? 0ull : (~0ull >> (64 - lane));
    int pos = __popcll(alive & ltmask);
    if ((alive >> lane) & 1ull) kept[b * PRE + cnt + pos] = (u32)(base + lane);
    cnt += (int)__popcll(alive);

    /* propagate suppression of kept rows to all future words */
#pragma unroll
    for (int k = 0; k < 64; ++k) {
      rem |= (((alive >> k) & 1ull) ? rows[k] : 0ull);
    }
    intra = intra_n;
  }
  if (lane == 0) info[16 + b] = (u32)cnt;
}

/* ---------- 10. output assembly ---------- */
__global__ void k_out(const float* __restrict__ boxes, const float* __restrict__ scoresel,
                      const u32* __restrict__ kept, const u32* __restrict__ info,
                      float* __restrict__ out) {
  int b = blockIdx.x, tid = threadIdx.x;                /* 256 */
  int cnt = (int)info[16 + b]; if (cnt > MAXOUT) cnt = MAXOUT;
  for (int k = tid; k < MAXOUT; k += 256) {
    float pr[6] = {0.f, 0.f, 0.f, 0.f, 0.f, 0.f};
    float s = 0.f, v = 0.f;
    if (k < cnt) {
      u32 i = kept[b * PRE + k];
      const float* bx = boxes + ((size_t)b * PRE + i) * 6;
#pragma unroll
      for (int d = 0; d < 6; ++d) pr[d] = bx[d];
      s = scoresel[b * PRE + i];
      v = 1.f;
    }
    float* pp = out + ((size_t)(b * MAXOUT + k)) * 6;
#pragma unroll
    for (int d = 0; d < 6; ++d) pp[d] = pr[d];
    out[BATCH * MAXOUT * 6 + b * MAXOUT + k] = s;
    out[BATCH * MAXOUT * 7 + b * MAXOUT + k] = (float)b;
    out[BATCH * MAXOUT * 8 + b * MAXOUT + k] = v;
  }
}

extern "C" void kernel_launch(void* const* d_in, const int* in_sizes, int n_in,
                              void* d_out, int out_size, void* d_ws, size_t ws_size,
                              hipStream_t stream) {
  const float* anchors = (const float*)d_in[0];
  const float* scores  = (const float*)d_in[1];
  const float* deltas  = (const float*)d_in[2];
  float* out = (float*)d_out;

  char* w = (char*)d_ws;
  u32* hist1   = (u32*)(w + OFF_HIST1);
  u32* hist2   = (u32*)(w + OFF_HIST2);
  u32* info    = (u32*)(w + OFF_INFO);
  u32* bcnt    = (u32*)(w + OFF_BCNT);
  u64* cand    = (u64*)(w + OFF_CAND);
  u32* order   = (u32*)(w + OFF_ORDER);
  float* scoresel = (float*)(w + OFF_SCORE);
  float* boxes = (float*)(w + OFF_BOXES);
  u64* masks   = (u64*)(w + OFF_MASKS);
  u32* kept    = (u32*)(w + OFF_KEPT);

  hipMemsetAsync(d_ws, 0, MEMSET_BYTES, stream);

  int nElem = BATCH * ANUM;
  k_hist1<<<nElem / 256, 256, 0, stream>>>(scores, hist1);
  k_sel1<<<BATCH, 256, 0, stream>>>(hist1, info);
  k_hist2<<<nElem / 256, 256, 0, stream>>>(scores, info, hist2);
  k_sel2<<<BATCH, 256, 0, stream>>>(hist2, info);
  k_compact<<<nElem / 256, 256, 0, stream>>>(scores, info, bcnt, cand);
  k_sort<<<BATCH, 1024, 0, stream>>>(cand, bcnt, order, scoresel);
  k_regress<<<(BATCH * PRE + 255) / 256, 256, 0, stream>>>(anchors, deltas, order, boxes);
  k_mask<<<dim3(NW, NW, BATCH), 64, 0, stream>>>(boxes, masks);
  k_scan<<<BATCH, 64, 0, stream>>>(masks, kept, info);
  k_out<<<BATCH, 256, 0, stream>>>(boxes, scoresel, kept, info, out);
}